// Round 12
// baseline (46.825 us; speedup 1.0000x reference)
//
#include <hip/hip_runtime.h>
#include <hip/hip_bf16.h>

// PointerNetwork: scores[b,d,e] = sum_h v[h]*tanh(dec_t[b,d,h] + enc_t[b,e,h]),
// out = log_softmax(scores, axis=e).  B=4, DEC=256, ENC=1024, H=256, fp32.
//
// tanh(a+b) = 1 - 2/(1 + e^{2a}e^{2b}).
//   K1 (MFMA bf16 + LDS dbuf): encE = exp2(SC*(x_enc.w1));
//       dec side writes decEi INTERLEAVED [dpair][h][2].
//   K2a scores: R11 post-mortem — SMEM (s_load) operands in the loop share
//       lgkmcnt with ds_read but complete out-of-order -> compiler emits
//       lgkmcnt(0) drains every group. This round the loop is PURE DS:
//       Es [64e][260] padded fp32 (imm offsets, ~2-way banks), decEi slice
//       + v staged in LDS, dq/wq via uniform-address ds_read_b128 broadcast.
//       d-pair packed float2 math (v_pk_*). 16 waves/block, 98KB LDS.
//   K2b lsm: in-place row log_softmax on d_out.

#define B_ 4
#define DEC_ 256
#define ENC_ 1024
#define H_ 256

using bf16x8 = __attribute__((ext_vector_type(8))) short;
using f32x4 = __attribute__((ext_vector_type(4))) float;
using f2 = __attribute__((ext_vector_type(2))) float;

__device__ inline short f2bf(float f) {
  union { float f; unsigned u; } x; x.f = f;
  return (short)((x.u + 0x8000u) >> 16);   // round-to-nearest
}

// ---------------- Kernel 1: dual GEMM (A . B^T) via MFMA + LDS dbuf ----------------
#define LDK 72   // padded row stride in shorts

__global__ __launch_bounds__(256) void gemm_mfma(
    const float* __restrict__ w1, const float* __restrict__ xe,
    const float* __restrict__ xd, const float* __restrict__ w2,
    float* __restrict__ encE, float* __restrict__ decEi) {
  const int blk = blockIdx.x;
  const float* A;
  const float* Bsrc;
  float* C;
  int ldc, m0, n0, decside;
  if (blk < 256) {
    const int b = blk >> 6;
    const int t = blk & 63;            // 4 (h) x 16 (e)
    m0 = (t >> 4) << 6; n0 = (t & 15) << 6;
    A = w1;
    Bsrc = xe + (size_t)b * ENC_ * H_;
    C = encE + (size_t)b * H_ * ENC_;
    ldc = ENC_;
    decside = 0;
  } else {
    const int blk2 = blk - 256;
    const int b = blk2 >> 4;
    const int t = blk2 & 15;           // 4 (d) x 4 (h)
    m0 = (t >> 2) << 6; n0 = (t & 3) << 6;
    A = xd + (size_t)b * DEC_ * H_;
    Bsrc = w2;
    C = decEi + (size_t)b * DEC_ * H_;
    ldc = H_;
    decside = 1;
  }
  const int K = H_;
  const int tid = threadIdx.x;
  const int wave = tid >> 6, lane = tid & 63;
  const int wm = (wave >> 1) << 5, wn = (wave & 1) << 5;
  const int fr = lane & 15;
  const int fk = (lane >> 4) << 3;

  __shared__ short As[2][64][LDK];
  __shared__ short Bs[2][64][LDK];

  const int srow = tid >> 2;
  const int skq = (tid & 3) << 4;
  const float* ag = A + (size_t)(m0 + srow) * K + skq;
  const float* bg = Bsrc + (size_t)(n0 + srow) * K + skq;

  float4 ra[4], rb[4];
#define LDCHUNK(K0)                                                    \
  {                                                                    \
    _Pragma("unroll")                                                  \
    for (int i = 0; i < 4; ++i) {                                      \
      ra[i] = *(const float4*)(ag + (K0) + 4 * i);                     \
      rb[i] = *(const float4*)(bg + (K0) + 4 * i);                     \
    }                                                                  \
  }
#define STCHUNK(BUF)                                                   \
  {                                                                    \
    _Pragma("unroll")                                                  \
    for (int j = 0; j < 2; ++j) {                                      \
      bf16x8 pa, pb;                                                   \
      pa[0] = f2bf(ra[2 * j].x);     pa[1] = f2bf(ra[2 * j].y);        \
      pa[2] = f2bf(ra[2 * j].z);     pa[3] = f2bf(ra[2 * j].w);        \
      pa[4] = f2bf(ra[2 * j + 1].x); pa[5] = f2bf(ra[2 * j + 1].y);    \
      pa[6] = f2bf(ra[2 * j + 1].z); pa[7] = f2bf(ra[2 * j + 1].w);    \
      pb[0] = f2bf(rb[2 * j].x);     pb[1] = f2bf(rb[2 * j].y);        \
      pb[2] = f2bf(rb[2 * j].z);     pb[3] = f2bf(rb[2 * j].w);        \
      pb[4] = f2bf(rb[2 * j + 1].x); pb[5] = f2bf(rb[2 * j + 1].y);    \
      pb[6] = f2bf(rb[2 * j + 1].z); pb[7] = f2bf(rb[2 * j + 1].w);    \
      *(bf16x8*)&As[BUF][srow][skq + 8 * j] = pa;                      \
      *(bf16x8*)&Bs[BUF][srow][skq + 8 * j] = pb;                      \
    }                                                                  \
  }

  f32x4 acc[2][2] = {};

#define COMPUTE(BUF)                                                   \
  {                                                                    \
    _Pragma("unroll")                                                  \
    for (int kk = 0; kk < 2; ++kk) {                                   \
      bf16x8 af[2], bff[2];                                            \
      _Pragma("unroll")                                                \
      for (int mi = 0; mi < 2; ++mi)                                   \
        af[mi] = *(const bf16x8*)&As[BUF][wm + (mi << 4) + fr][(kk << 5) + fk]; \
      _Pragma("unroll")                                                \
      for (int ni = 0; ni < 2; ++ni)                                   \
        bff[ni] = *(const bf16x8*)&Bs[BUF][wn + (ni << 4) + fr][(kk << 5) + fk]; \
      _Pragma("unroll")                                                \
      for (int mi = 0; mi < 2; ++mi)                                   \
        _Pragma("unroll")                                              \
        for (int ni = 0; ni < 2; ++ni)                                 \
          acc[mi][ni] = __builtin_amdgcn_mfma_f32_16x16x32_bf16(       \
              af[mi], bff[ni], acc[mi][ni], 0, 0, 0);                  \
    }                                                                  \
  }

  LDCHUNK(0)
  STCHUNK(0)
  __syncthreads();
  LDCHUNK(64) COMPUTE(0) STCHUNK(1) __syncthreads();
  LDCHUNK(128) COMPUTE(1) STCHUNK(0) __syncthreads();
  LDCHUNK(192) COMPUTE(0) STCHUNK(1) __syncthreads();
  COMPUTE(1)

  const float SC = 2.8853900817779268f;  // 2*log2(e)
#pragma unroll
  for (int mi = 0; mi < 2; ++mi) {
#pragma unroll
    for (int ni = 0; ni < 2; ++ni) {
      const int row = m0 + wm + (mi << 4) + ((lane >> 4) << 2);
      const int col = n0 + wn + (ni << 4) + (lane & 15);
#pragma unroll
      for (int r = 0; r < 4; ++r) {
        const float val = __builtin_amdgcn_exp2f(acc[mi][ni][r] * SC);
        if (decside) {
          // interleaved: [(d>>1)][h][d&1]
          const int rr = row + r;
          C[((size_t)(rr >> 1) * H_ + col) * 2 + (rr & 1)] = val;
        } else {
          C[(size_t)(row + r) * ldc + col] = val;
        }
      }
    }
  }
}

// ---------------- Kernel 2a: raw scores (pure-DS hot loop) ----------------
// Block = 1024 thr = 16 waves; covers 64 e x 32 d. LDS: Es [64][260] fp32
// (padded -> imm offsets, ~2-way banks), Ds [16 pair][256h][2], Vs [256].
// Per 4h-group: 1 per-lane ds_read_b128 (E) + 3 uniform ds_read_b128
// broadcasts (dq x2, wv) + 14 pk-VALU + 2 rcp. No SMEM/global in loop.
// Writes raw -2*acc (vsum cancels in log_softmax). Grid 512 -> 1 blk/CU.

#define EPAD 260

__global__ __launch_bounds__(1024) void scores_k(
    const float* __restrict__ encE, const float* __restrict__ decEi,
    const float* __restrict__ v, float* __restrict__ out) {
  const int bid = blockIdx.x;            // 0..511
  // XCD pinning: batch b -> XCDs {2b, 2b+1}
  const int xcd = bid & 7;
  const int b = xcd >> 1;
  const int rem = ((bid >> 3) << 1) | (xcd & 1);   // 0..127 within batch
  const int es = rem & 15;               // e-slice (64 e)
  const int d0 = (rem >> 4) << 5;        // d-group of 32
  const int tid = threadIdx.x;
  const int lane = tid & 63;
  const int wid = __builtin_amdgcn_readfirstlane(tid >> 6);  // 0..15

  __shared__ __align__(16) float Es[64 * EPAD];  // [e][h] padded
  __shared__ __align__(16) float Ds[16 * 512];   // [pair][h][2]
  __shared__ __align__(16) float Vs[H_];

  const int e0 = es << 6;
  const float* egbase = encE + (size_t)b * H_ * ENC_ + e0;

  // ---- stage Es (transpose): 4 float4 loads, 16 ds_writes / thread ----
#pragma unroll
  for (int s = 0; s < 4; ++s) {
    const int fi = (s << 10) + tid;      // 0..4095
    const int h = fi >> 4;               // 0..255
    const int c = fi & 15;               // float4 chunk along e
    const float4 x = *(const float4*)(egbase + (size_t)h * ENC_ + (c << 2));
#pragma unroll
    for (int j = 0; j < 4; ++j) {
      const int r = (c << 2) + j;        // e-row 0..63
      Es[r * EPAD + h] = ((const float*)&x)[j];
    }
  }
  // ---- stage Ds: 16 pairs x 512 floats contiguous in decEi ----
  {
    const float* dsrc = decEi + (size_t)b * DEC_ * H_ + (size_t)(d0 >> 1) * (2 * H_);
    *(float4*)&Ds[tid << 2] = *(const float4*)(dsrc + (tid << 2));
    *(float4*)&Ds[4096 + (tid << 2)] = *(const float4*)(dsrc + 4096 + (tid << 2));
  }
  if (tid < H_ / 4) *(float4*)&Vs[tid << 2] = *(const float4*)(v + (tid << 2));
  __syncthreads();

  const float* dpl = &Ds[wid << 9];      // wave-uniform pair row (512 floats)
  const float* eptr = &Es[lane * EPAD];

  f2 acc = {0.0f, 0.0f};
  const f2 one = {1.0f, 1.0f};

#pragma unroll 8
  for (int g = 0; g < 64; ++g) {
    const float4 E4 = *(const float4*)(eptr + (g << 2));       // imm offset
    const f2* dq = (const f2*)(dpl + (g << 3));                // uniform bcast
    const float4 wv = *(const float4*)(&Vs[g << 2]);           // uniform bcast
    const f2 m0 = f2{E4.x, E4.x} * dq[0] + one;
    const f2 m1 = f2{E4.y, E4.y} * dq[1] + one;
    const f2 m2 = f2{E4.z, E4.z} * dq[2] + one;
    const f2 m3 = f2{E4.w, E4.w} * dq[3] + one;
    const f2 pa = m0 * m1, pb = m2 * m3;
    const f2 n01 = f2{wv.x, wv.x} * m1 + f2{wv.y, wv.y} * m0;
    const f2 n23 = f2{wv.z, wv.z} * m3 + f2{wv.w, wv.w} * m2;
    const f2 num = n01 * pb + n23 * pa;
    const f2 den = pa * pb;
    const f2 r = {__builtin_amdgcn_rcpf(den.x), __builtin_amdgcn_rcpf(den.y)};
    acc = num * r + acc;
  }

  const int d = d0 + (wid << 1);
  float* orow = out + (size_t)(b * DEC_ + d) * ENC_ + e0 + lane;
  orow[0] = -2.0f * acc.x;
  orow[ENC_] = -2.0f * acc.y;
}

// ---------------- Kernel 2b: in-place row log_softmax ----------------
// 1 row (1024 f32) per block, 256 thr x float4.

__global__ __launch_bounds__(256) void lsm_k(float* __restrict__ out) {
  const int row = blockIdx.x;            // 0..1023
  float* p = out + (size_t)row * ENC_;
  const int tid = threadIdx.x;
  const int lane = tid & 63, wid = tid >> 6;

  __shared__ float rm[4], rs[4];

  float4 x = *(const float4*)(p + 4 * tid);

  float m = fmaxf(fmaxf(x.x, x.y), fmaxf(x.z, x.w));
#pragma unroll
  for (int o = 32; o >= 1; o >>= 1) m = fmaxf(m, __shfl_xor(m, o, 64));
  if (lane == 0) rm[wid] = m;
  __syncthreads();
  const float M = fmaxf(fmaxf(rm[0], rm[1]), fmaxf(rm[2], rm[3]));

  const float L2E = 1.4426950408889634f;
  const float LN2 = 0.6931471805599453f;
  float z = __builtin_amdgcn_exp2f((x.x - M) * L2E) +
            __builtin_amdgcn_exp2f((x.y - M) * L2E) +
            __builtin_amdgcn_exp2f((x.z - M) * L2E) +
            __builtin_amdgcn_exp2f((x.w - M) * L2E);
#pragma unroll
  for (int o = 32; o >= 1; o >>= 1) z += __shfl_xor(z, o, 64);
  if (lane == 0) rs[wid] = z;
  __syncthreads();
  const float S = (rs[0] + rs[1]) + (rs[2] + rs[3]);

  const float lse = M + LN2 * __builtin_amdgcn_logf(S);
  x.x -= lse; x.y -= lse; x.z -= lse; x.w -= lse;
  *(float4*)(p + 4 * tid) = x;
}

extern "C" void kernel_launch(void* const* d_in, const int* in_sizes, int n_in,
                              void* d_out, int out_size, void* d_ws, size_t ws_size,
                              hipStream_t stream) {
  const float* xd = (const float*)d_in[0];  // (4,256,256)
  const float* xe = (const float*)d_in[1];  // (4,1024,256)
  const float* w1 = (const float*)d_in[2];  // (256,256)
  const float* w2 = (const float*)d_in[3];  // (256,256)
  const float* v  = (const float*)d_in[4];  // (256,)
  float* out = (float*)d_out;               // (4,256,1024)

  float* encE = (float*)d_ws;                          // 4 MB: [B][H][ENC]
  float* decEi = encE + (size_t)B_ * H_ * ENC_;        // 1 MB: [B][dpair][H][2]

  gemm_mfma<<<320, 256, 0, stream>>>(w1, xe, xd, w2, encE, decEi);
  scores_k<<<512, 1024, 0, stream>>>(encE, decEi, v, out);
  lsm_k<<<B_ * DEC_, 256, 0, stream>>>(out);
}

// Round 13
// 45.108 us; speedup vs baseline: 1.0381x; 1.0381x over previous
//
#include <hip/hip_runtime.h>
#include <hip/hip_bf16.h>

// PointerNetwork: scores[b,d,e] = sum_h v[h]*tanh(dec_t[b,d,h] + enc_t[b,e,h]),
// out = log_softmax(scores, axis=e).  B=4, DEC=256, ENC=1024, H=256, fp32.
//
// tanh(a+b) = 1 - 2/(1 + e^{2a}e^{2b}).
//   K1 (MFMA bf16 + LDS dbuf): encE = exp2(SC*(x_enc.w1)), decE = exp2(SC*(x_dec.w2))
//   K2a scores (R12 post-mortem: pure-DS regressed; operand-path theory):
//       e-PAIR packing: lane owns e-pair -> E arrives as packed reg pairs from
//       one ds_read_b128; d is wave-uniform -> decE/v operands are SGPR
//       scalars broadcast free into VOP3P halves. Wave = 2d x 128e; block =
//       512 thr = 16d x 128e; Es [64ep][h][2] stride-260, 128-h halves.
//   K2b lsm: in-place row log_softmax on d_out.

#define B_ 4
#define DEC_ 256
#define ENC_ 1024
#define H_ 256

using bf16x8 = __attribute__((ext_vector_type(8))) short;
using f32x4 = __attribute__((ext_vector_type(4))) float;
using f2 = __attribute__((ext_vector_type(2))) float;

__device__ inline short f2bf(float f) {
  union { float f; unsigned u; } x; x.f = f;
  return (short)((x.u + 0x8000u) >> 16);   // round-to-nearest
}

__device__ inline f2 bc(float s) { return f2{s, s}; }

// ---------------- Kernel 1: dual GEMM (A . B^T) via MFMA + LDS dbuf ----------------
#define LDK 72   // padded row stride in shorts

__global__ __launch_bounds__(256) void gemm_mfma(
    const float* __restrict__ w1, const float* __restrict__ xe,
    const float* __restrict__ xd, const float* __restrict__ w2,
    float* __restrict__ encE, float* __restrict__ decE) {
  const int blk = blockIdx.x;
  const float* A;
  const float* Bsrc;
  float* C;
  int ldc, m0, n0;
  if (blk < 256) {
    const int b = blk >> 6;
    const int t = blk & 63;            // 4 (h) x 16 (e)
    m0 = (t >> 4) << 6; n0 = (t & 15) << 6;
    A = w1;
    Bsrc = xe + (size_t)b * ENC_ * H_;
    C = encE + (size_t)b * H_ * ENC_;
    ldc = ENC_;
  } else {
    const int blk2 = blk - 256;
    const int b = blk2 >> 4;
    const int t = blk2 & 15;           // 4 (d) x 4 (h)
    m0 = (t >> 2) << 6; n0 = (t & 3) << 6;
    A = xd + (size_t)b * DEC_ * H_;
    Bsrc = w2;
    C = decE + (size_t)b * DEC_ * H_;
    ldc = H_;
  }
  const int K = H_;
  const int tid = threadIdx.x;
  const int wave = tid >> 6, lane = tid & 63;
  const int wm = (wave >> 1) << 5, wn = (wave & 1) << 5;
  const int fr = lane & 15;
  const int fk = (lane >> 4) << 3;

  __shared__ short As[2][64][LDK];
  __shared__ short Bs[2][64][LDK];

  const int srow = tid >> 2;
  const int skq = (tid & 3) << 4;
  const float* ag = A + (size_t)(m0 + srow) * K + skq;
  const float* bg = Bsrc + (size_t)(n0 + srow) * K + skq;

  float4 ra[4], rb[4];
#define LDCHUNK(K0)                                                    \
  {                                                                    \
    _Pragma("unroll")                                                  \
    for (int i = 0; i < 4; ++i) {                                      \
      ra[i] = *(const float4*)(ag + (K0) + 4 * i);                     \
      rb[i] = *(const float4*)(bg + (K0) + 4 * i);                     \
    }                                                                  \
  }
#define STCHUNK(BUF)                                                   \
  {                                                                    \
    _Pragma("unroll")                                                  \
    for (int j = 0; j < 2; ++j) {                                      \
      bf16x8 pa, pb;                                                   \
      pa[0] = f2bf(ra[2 * j].x);     pa[1] = f2bf(ra[2 * j].y);        \
      pa[2] = f2bf(ra[2 * j].z);     pa[3] = f2bf(ra[2 * j].w);        \
      pa[4] = f2bf(ra[2 * j + 1].x); pa[5] = f2bf(ra[2 * j + 1].y);    \
      pa[6] = f2bf(ra[2 * j + 1].z); pa[7] = f2bf(ra[2 * j + 1].w);    \
      pb[0] = f2bf(rb[2 * j].x);     pb[1] = f2bf(rb[2 * j].y);        \
      pb[2] = f2bf(rb[2 * j].z);     pb[3] = f2bf(rb[2 * j].w);        \
      pb[4] = f2bf(rb[2 * j + 1].x); pb[5] = f2bf(rb[2 * j + 1].y);    \
      pb[6] = f2bf(rb[2 * j + 1].z); pb[7] = f2bf(rb[2 * j + 1].w);    \
      *(bf16x8*)&As[BUF][srow][skq + 8 * j] = pa;                      \
      *(bf16x8*)&Bs[BUF][srow][skq + 8 * j] = pb;                      \
    }                                                                  \
  }

  f32x4 acc[2][2] = {};

#define COMPUTE(BUF)                                                   \
  {                                                                    \
    _Pragma("unroll")                                                  \
    for (int kk = 0; kk < 2; ++kk) {                                   \
      bf16x8 af[2], bff[2];                                            \
      _Pragma("unroll")                                                \
      for (int mi = 0; mi < 2; ++mi)                                   \
        af[mi] = *(const bf16x8*)&As[BUF][wm + (mi << 4) + fr][(kk << 5) + fk]; \
      _Pragma("unroll")                                                \
      for (int ni = 0; ni < 2; ++ni)                                   \
        bff[ni] = *(const bf16x8*)&Bs[BUF][wn + (ni << 4) + fr][(kk << 5) + fk]; \
      _Pragma("unroll")                                                \
      for (int mi = 0; mi < 2; ++mi)                                   \
        _Pragma("unroll")                                              \
        for (int ni = 0; ni < 2; ++ni)                                 \
          acc[mi][ni] = __builtin_amdgcn_mfma_f32_16x16x32_bf16(       \
              af[mi], bff[ni], acc[mi][ni], 0, 0, 0);                  \
    }                                                                  \
  }

  LDCHUNK(0)
  STCHUNK(0)
  __syncthreads();
  LDCHUNK(64) COMPUTE(0) STCHUNK(1) __syncthreads();
  LDCHUNK(128) COMPUTE(1) STCHUNK(0) __syncthreads();
  LDCHUNK(192) COMPUTE(0) STCHUNK(1) __syncthreads();
  COMPUTE(1)

  const float SC = 2.8853900817779268f;  // 2*log2(e)
#pragma unroll
  for (int mi = 0; mi < 2; ++mi) {
#pragma unroll
    for (int ni = 0; ni < 2; ++ni) {
      const int row = m0 + wm + (mi << 4) + ((lane >> 4) << 2);
      const int col = n0 + wn + (ni << 4) + (lane & 15);
#pragma unroll
      for (int r = 0; r < 4; ++r)
        C[(size_t)(row + r) * ldc + col] =
            __builtin_amdgcn_exp2f(acc[mi][ni][r] * SC);
    }
  }
}

// ---------------- Kernel 2a: raw scores (e-pair packed, scalar d operands) ----------------
// Block = 512 thr = 8 waves; wave w owns d-pair, all waves share the block's
// 128-e slice. Lane owns e-pair (2*lane, 2*lane+1) -> one ds_read_b128 gives
// 2 h x 2 e packed; decE/v are wave-uniform scalars (SGPR broadcast in VOP3P).
// Es = [64 ep][h][2] fp32, row stride 260 (16B aligned, spread banks), staged
// in two 128-h halves (66KB LDS). Writes raw -2*acc. Grid 512 -> 2 blk/CU.

#define ESTR 260

// 4 h-terms for one d (scalars q0..q3, w0..w3), 2 packed e's -> acc A0,A1
#define TANH4(Ea, Eb, Q, W, A0, A1)                                    \
  {                                                                    \
    const f2 m0 = f2{Ea.x, Ea.y} * bc(Q[0]) + one;                     \
    const f2 m1 = f2{Ea.z, Ea.w} * bc(Q[1]) + one;                     \
    const f2 m2 = f2{Eb.x, Eb.y} * bc(Q[2]) + one;                     \
    const f2 m3 = f2{Eb.z, Eb.w} * bc(Q[3]) + one;                     \
    const f2 pa = m0 * m1, pb = m2 * m3;                               \
    const f2 n01 = bc(W[0]) * m1 + bc(W[1]) * m0;                      \
    const f2 n23 = bc(W[2]) * m3 + bc(W[3]) * m2;                      \
    const f2 num = n01 * pb + n23 * pa;                                \
    const f2 den = pa * pb;                                            \
    A0 += num.x * __builtin_amdgcn_rcpf(den.x);                        \
    A1 += num.y * __builtin_amdgcn_rcpf(den.y);                        \
  }

__global__ __launch_bounds__(512) void scores_k(
    const float* __restrict__ encE, const float* __restrict__ decE,
    const float* __restrict__ v, float* __restrict__ out) {
  const int bid = blockIdx.x;            // 0..511
  // XCD pinning: batch b -> XCDs {2b, 2b+1}
  const int xcd = bid & 7;
  const int b = xcd >> 1;
  const int rem = ((bid >> 3) << 1) | (xcd & 1);   // 0..127 within batch
  const int es = rem & 7;                // 128-e slice
  const int dg = rem >> 3;               // 0..15 -> 16-d group
  const int tid = threadIdx.x;
  const int lane = tid & 63;

  __shared__ __align__(16) float Es[64 * ESTR];   // [ep][h(128)][2], padded

  const int e0 = es << 7;
  const int du = __builtin_amdgcn_readfirstlane((dg << 4) + ((tid >> 6) << 1));
  const float* dp0 = decE + (size_t)(b * DEC_ + du) * H_;   // SGPR base
  const float* dp1 = dp0 + H_;

  float a00 = 0.f, a01 = 0.f, a10 = 0.f, a11 = 0.f;   // [d][e-parity]
  const f2 one = {1.0f, 1.0f};

#define STAGE(C2)                                                      \
  {                                                                    \
    const float* src = encE + (size_t)b * H_ * ENC_ +                  \
                       (size_t)(C2) * 128 * ENC_ + e0;                 \
    _Pragma("unroll")                                                  \
    for (int s = 0; s < 8; ++s) {                                      \
      const int fi = (s << 9) + tid;     /* 0..4095 */                 \
      const int hl = fi >> 5;            /* 0..127 */                  \
      const int c = fi & 31;             /* float4 along e */          \
      const float4 x = *(const float4*)(src + (size_t)hl * ENC_ + (c << 2)); \
      *(f2*)&Es[(2 * c) * ESTR + 2 * hl] = f2{x.x, x.y};               \
      *(f2*)&Es[(2 * c + 1) * ESTR + 2 * hl] = f2{x.z, x.w};           \
    }                                                                  \
  }

#define CHUNKS(C2)                                                     \
  {                                                                    \
    _Pragma("unroll")                                                  \
    for (int sc = 0; sc < 8; ++sc) {     /* 16-h scalar chunks */      \
      const int hb = (C2)*128 + (sc << 4);                             \
      float q0[16], q1[16], wv[16];                                    \
      _Pragma("unroll")                                                \
      for (int i = 0; i < 16; ++i) {                                   \
        q0[i] = dp0[hb + i]; q1[i] = dp1[hb + i]; wv[i] = v[hb + i];   \
      }                                                                \
      _Pragma("unroll")                                                \
      for (int g = 0; g < 4; ++g) {      /* 4h bundles */              \
        const int hl = (sc << 4) + (g << 2);  /* h within half */      \
        const float4 Ea = *(const float4*)&Es[lane * ESTR + 2 * hl];   \
        const float4 Eb = *(const float4*)&Es[lane * ESTR + 2 * hl + 4]; \
        TANH4(Ea, Eb, (&q0[g << 2]), (&wv[g << 2]), a00, a01)          \
        TANH4(Ea, Eb, (&q1[g << 2]), (&wv[g << 2]), a10, a11)          \
      }                                                                \
    }                                                                  \
  }

  STAGE(0)
  __syncthreads();
  CHUNKS(0)
  __syncthreads();
  STAGE(1)
  __syncthreads();
  CHUNKS(1)

  float* o0 = out + (size_t)(b * DEC_ + du) * ENC_ + e0 + (lane << 1);
  *(f2*)o0 = f2{-2.0f * a00, -2.0f * a01};
  *(f2*)(o0 + ENC_) = f2{-2.0f * a10, -2.0f * a11};
}

// ---------------- Kernel 2b: in-place row log_softmax ----------------
// 1 row (1024 f32) per block, 256 thr x float4.

__global__ __launch_bounds__(256) void lsm_k(float* __restrict__ out) {
  const int row = blockIdx.x;            // 0..1023
  float* p = out + (size_t)row * ENC_;
  const int tid = threadIdx.x;
  const int lane = tid & 63, wid = tid >> 6;

  __shared__ float rm[4], rs[4];

  float4 x = *(const float4*)(p + 4 * tid);

  float m = fmaxf(fmaxf(x.x, x.y), fmaxf(x.z, x.w));
#pragma unroll
  for (int o = 32; o >= 1; o >>= 1) m = fmaxf(m, __shfl_xor(m, o, 64));
  if (lane == 0) rm[wid] = m;
  __syncthreads();
  const float M = fmaxf(fmaxf(rm[0], rm[1]), fmaxf(rm[2], rm[3]));

  const float L2E = 1.4426950408889634f;
  const float LN2 = 0.6931471805599453f;
  float z = __builtin_amdgcn_exp2f((x.x - M) * L2E) +
            __builtin_amdgcn_exp2f((x.y - M) * L2E) +
            __builtin_amdgcn_exp2f((x.z - M) * L2E) +
            __builtin_amdgcn_exp2f((x.w - M) * L2E);
#pragma unroll
  for (int o = 32; o >= 1; o >>= 1) z += __shfl_xor(z, o, 64);
  if (lane == 0) rs[wid] = z;
  __syncthreads();
  const float S = (rs[0] + rs[1]) + (rs[2] + rs[3]);

  const float lse = M + LN2 * __builtin_amdgcn_logf(S);
  x.x -= lse; x.y -= lse; x.z -= lse; x.w -= lse;
  *(float4*)(p + 4 * tid) = x;
}

extern "C" void kernel_launch(void* const* d_in, const int* in_sizes, int n_in,
                              void* d_out, int out_size, void* d_ws, size_t ws_size,
                              hipStream_t stream) {
  const float* xd = (const float*)d_in[0];  // (4,256,256)
  const float* xe = (const float*)d_in[1];  // (4,1024,256)
  const float* w1 = (const float*)d_in[2];  // (256,256)
  const float* w2 = (const float*)d_in[3];  // (256,256)
  const float* v  = (const float*)d_in[4];  // (256,)
  float* out = (float*)d_out;               // (4,256,1024)

  float* encE = (float*)d_ws;                          // 4 MB: [B][H][ENC]
  float* decE = encE + (size_t)B_ * H_ * ENC_;         // 1 MB: [B][DEC][H]

  gemm_mfma<<<320, 256, 0, stream>>>(w1, xe, xd, w2, encE, decE);
  scores_k<<<512, 512, 0, stream>>>(encE, decE, v, out);
  lsm_k<<<B_ * DEC_, 256, 0, stream>>>(out);
}

// Round 14
// 43.516 us; speedup vs baseline: 1.0760x; 1.0366x over previous
//
#include <hip/hip_runtime.h>
#include <hip/hip_bf16.h>

// PointerNetwork: scores[b,d,e] = sum_h v[h]*tanh(dec_t[b,d,h] + enc_t[b,e,h]),
// out = log_softmax(scores, axis=e).  B=4, DEC=256, ENC=1024, H=256, fp32.
//
// tanh(a+b) = 1 - 2/(1 + e^{2a}e^{2b}).
//   K1 (MFMA bf16 + LDS dbuf): encE = exp2(SC*(x_enc.w1));
//       dec side writes decEi INTERLEAVED [dpair][h][2].
//   K2a scores (R13 post-mortem: R11's f2 "packed" loop was almost certainly
//       scalarized -> busy = 2x the VOP3P model). This round: R11 structure
//       with the bundle hand-written in inline-asm v_pk_fma_f32/v_pk_mul_f32;
//       E scalars broadcast via op_sel on aligned ds_read_b64 pairs; dq/w as
//       SGPR-pair operands (1 sgpr/inst). 14 pk + 2 rcp per 8 elements.
//   K2b lsm: in-place row log_softmax on d_out.

#define B_ 4
#define DEC_ 256
#define ENC_ 1024
#define H_ 256

using bf16x8 = __attribute__((ext_vector_type(8))) short;
using f32x4 = __attribute__((ext_vector_type(4))) float;
using f2 = __attribute__((ext_vector_type(2))) float;

__device__ inline short f2bf(float f) {
  union { float f; unsigned u; } x; x.f = f;
  return (short)((x.u + 0x8000u) >> 16);   // round-to-nearest
}

// ---- forced VOP3P packed-f32 helpers ----
// plain (all-VGPR)
static __device__ __forceinline__ f2 pk_mul(f2 a, f2 b) {
  f2 d; asm("v_pk_mul_f32 %0, %1, %2" : "=v"(d) : "v"(a), "v"(b)); return d;
}
static __device__ __forceinline__ f2 pk_fma(f2 a, f2 b, f2 c) {
  f2 d; asm("v_pk_fma_f32 %0, %1, %2, %3" : "=v"(d) : "v"(a), "v"(b), "v"(c)); return d;
}
// m = dq * bcast(E.lo) + c   (dq in SGPR pair; e01 aligned VGPR pair)
static __device__ __forceinline__ f2 pk_fma_dq_elo(f2 dq, f2 e01, f2 c) {
  f2 d; asm("v_pk_fma_f32 %0, %1, %2, %3 op_sel:[0,0,0] op_sel_hi:[1,0,1]"
            : "=v"(d) : "s"(dq), "v"(e01), "v"(c)); return d;
}
// m = dq * bcast(E.hi) + c
static __device__ __forceinline__ f2 pk_fma_dq_ehi(f2 dq, f2 e01, f2 c) {
  f2 d; asm("v_pk_fma_f32 %0, %1, %2, %3 op_sel:[0,1,0] op_sel_hi:[1,1,1]"
            : "=v"(d) : "s"(dq), "v"(e01), "v"(c)); return d;
}
// t = bcast(w.lo) * m   (w in SGPR pair)
static __device__ __forceinline__ f2 pk_mul_wlo(f2 w, f2 m) {
  f2 d; asm("v_pk_mul_f32 %0, %1, %2 op_sel:[0,0] op_sel_hi:[0,1]"
            : "=v"(d) : "s"(w), "v"(m)); return d;
}
// n = bcast(w.hi) * m + t
static __device__ __forceinline__ f2 pk_fma_whi(f2 w, f2 m, f2 c) {
  f2 d; asm("v_pk_fma_f32 %0, %1, %2, %3 op_sel:[1,0,0] op_sel_hi:[1,1,1]"
            : "=v"(d) : "s"(w), "v"(m), "v"(c)); return d;
}

// ---------------- Kernel 1: dual GEMM (A . B^T) via MFMA + LDS dbuf ----------------
#define LDK 72   // padded row stride in shorts

__global__ __launch_bounds__(256) void gemm_mfma(
    const float* __restrict__ w1, const float* __restrict__ xe,
    const float* __restrict__ xd, const float* __restrict__ w2,
    float* __restrict__ encE, float* __restrict__ decEi) {
  const int blk = blockIdx.x;
  const float* A;
  const float* Bsrc;
  float* C;
  int ldc, m0, n0, decside;
  if (blk < 256) {
    const int b = blk >> 6;
    const int t = blk & 63;            // 4 (h) x 16 (e)
    m0 = (t >> 4) << 6; n0 = (t & 15) << 6;
    A = w1;
    Bsrc = xe + (size_t)b * ENC_ * H_;
    C = encE + (size_t)b * H_ * ENC_;
    ldc = ENC_;
    decside = 0;
  } else {
    const int blk2 = blk - 256;
    const int b = blk2 >> 4;
    const int t = blk2 & 15;           // 4 (d) x 4 (h)
    m0 = (t >> 2) << 6; n0 = (t & 3) << 6;
    A = xd + (size_t)b * DEC_ * H_;
    Bsrc = w2;
    C = decEi + (size_t)b * DEC_ * H_;
    ldc = H_;
    decside = 1;
  }
  const int K = H_;
  const int tid = threadIdx.x;
  const int wave = tid >> 6, lane = tid & 63;
  const int wm = (wave >> 1) << 5, wn = (wave & 1) << 5;
  const int fr = lane & 15;
  const int fk = (lane >> 4) << 3;

  __shared__ short As[2][64][LDK];
  __shared__ short Bs[2][64][LDK];

  const int srow = tid >> 2;
  const int skq = (tid & 3) << 4;
  const float* ag = A + (size_t)(m0 + srow) * K + skq;
  const float* bg = Bsrc + (size_t)(n0 + srow) * K + skq;

  float4 ra[4], rb[4];
#define LDCHUNK(K0)                                                    \
  {                                                                    \
    _Pragma("unroll")                                                  \
    for (int i = 0; i < 4; ++i) {                                      \
      ra[i] = *(const float4*)(ag + (K0) + 4 * i);                     \
      rb[i] = *(const float4*)(bg + (K0) + 4 * i);                     \
    }                                                                  \
  }
#define STCHUNK(BUF)                                                   \
  {                                                                    \
    _Pragma("unroll")                                                  \
    for (int j = 0; j < 2; ++j) {                                      \
      bf16x8 pa, pb;                                                   \
      pa[0] = f2bf(ra[2 * j].x);     pa[1] = f2bf(ra[2 * j].y);        \
      pa[2] = f2bf(ra[2 * j].z);     pa[3] = f2bf(ra[2 * j].w);        \
      pa[4] = f2bf(ra[2 * j + 1].x); pa[5] = f2bf(ra[2 * j + 1].y);    \
      pa[6] = f2bf(ra[2 * j + 1].z); pa[7] = f2bf(ra[2 * j + 1].w);    \
      pb[0] = f2bf(rb[2 * j].x);     pb[1] = f2bf(rb[2 * j].y);        \
      pb[2] = f2bf(rb[2 * j].z);     pb[3] = f2bf(rb[2 * j].w);        \
      pb[4] = f2bf(rb[2 * j + 1].x); pb[5] = f2bf(rb[2 * j + 1].y);    \
      pb[6] = f2bf(rb[2 * j + 1].z); pb[7] = f2bf(rb[2 * j + 1].w);    \
      *(bf16x8*)&As[BUF][srow][skq + 8 * j] = pa;                      \
      *(bf16x8*)&Bs[BUF][srow][skq + 8 * j] = pb;                      \
    }                                                                  \
  }

  f32x4 acc[2][2] = {};

#define COMPUTE(BUF)                                                   \
  {                                                                    \
    _Pragma("unroll")                                                  \
    for (int kk = 0; kk < 2; ++kk) {                                   \
      bf16x8 af[2], bff[2];                                            \
      _Pragma("unroll")                                                \
      for (int mi = 0; mi < 2; ++mi)                                   \
        af[mi] = *(const bf16x8*)&As[BUF][wm + (mi << 4) + fr][(kk << 5) + fk]; \
      _Pragma("unroll")                                                \
      for (int ni = 0; ni < 2; ++ni)                                   \
        bff[ni] = *(const bf16x8*)&Bs[BUF][wn + (ni << 4) + fr][(kk << 5) + fk]; \
      _Pragma("unroll")                                                \
      for (int mi = 0; mi < 2; ++mi)                                   \
        _Pragma("unroll")                                              \
        for (int ni = 0; ni < 2; ++ni)                                 \
          acc[mi][ni] = __builtin_amdgcn_mfma_f32_16x16x32_bf16(       \
              af[mi], bff[ni], acc[mi][ni], 0, 0, 0);                  \
    }                                                                  \
  }

  LDCHUNK(0)
  STCHUNK(0)
  __syncthreads();
  LDCHUNK(64) COMPUTE(0) STCHUNK(1) __syncthreads();
  LDCHUNK(128) COMPUTE(1) STCHUNK(0) __syncthreads();
  LDCHUNK(192) COMPUTE(0) STCHUNK(1) __syncthreads();
  COMPUTE(1)

  const float SC = 2.8853900817779268f;  // 2*log2(e)
#pragma unroll
  for (int mi = 0; mi < 2; ++mi) {
#pragma unroll
    for (int ni = 0; ni < 2; ++ni) {
      const int row = m0 + wm + (mi << 4) + ((lane >> 4) << 2);
      const int col = n0 + wn + (ni << 4) + (lane & 15);
#pragma unroll
      for (int r = 0; r < 4; ++r) {
        const float val = __builtin_amdgcn_exp2f(acc[mi][ni][r] * SC);
        if (decside) {
          // interleaved: [(d>>1)][h][d&1]
          const int rr = row + r;
          C[((size_t)(rr >> 1) * H_ + col) * 2 + (rr & 1)] = val;
        } else {
          C[(size_t)(row + r) * ldc + col] = val;
        }
      }
    }
  }
}

// ---------------- Kernel 2a: raw scores (forced VOP3P, d-pair packed) ----------------
// R11 structure: block = 1024 thr = 16 waves, covers 64 e x 32 d; Es [64e][256h]
// staged transposed + XOR-swizzled; wave w owns d-pair (via interleaved decEi).
// Bundle (4h x 2d = 8 elems): 2 ds_read_b64 (E pairs) + 14 v_pk ops + 2 rcp;
// dq/w operands are SGPR pairs (uniform s_loads), E broadcast via op_sel.
// Writes raw -2*acc (vsum cancels in log_softmax). Grid 512 -> 2 blk/CU.

__global__ __launch_bounds__(1024) void scores_k(
    const float* __restrict__ encE, const float* __restrict__ decEi,
    const float* __restrict__ v, float* __restrict__ out) {
  const int bid = blockIdx.x;            // 0..511
  // XCD pinning: batch b -> XCDs {2b, 2b+1}
  const int xcd = bid & 7;
  const int b = xcd >> 1;
  const int rem = ((bid >> 3) << 1) | (xcd & 1);   // 0..127 within batch
  const int es = rem & 15;               // e-slice (64 e)
  const int d0 = (rem >> 4) << 5;        // d-group of 32
  const int tid = threadIdx.x;
  const int lane = tid & 63;
  const int wid = __builtin_amdgcn_readfirstlane(tid >> 6);  // 0..15

  __shared__ __align__(16) float Es[64 * 256];   // [e-row][h], swizzled chunks

  const int e0 = es << 6;
  const float* egbase = encE + (size_t)b * H_ * ENC_ + e0;

  // ---- stage Es (transpose + XOR swizzle): 4 float4 loads, 16 ds_writes ----
#pragma unroll
  for (int s = 0; s < 4; ++s) {
    const int fi = (s << 10) + tid;      // 0..4095
    const int h = fi >> 4;               // 0..255
    const int c = fi & 15;               // float4 chunk along e
    const float4 x = *(const float4*)(egbase + (size_t)h * ENC_ + (c << 2));
    const int g = h >> 2, ho = h & 3;
#pragma unroll
    for (int j = 0; j < 4; ++j) {
      const int r = (c << 2) + j;        // e-row 0..63
      Es[(r << 8) + ((g ^ (r & 7)) << 2) + ho] = ((const float*)&x)[j];
    }
  }
  __syncthreads();

  const int dpair = (d0 >> 1) + wid;     // d = 2*dpair, 2*dpair+1
  const float* dpi = decEi + (size_t)b * DEC_ * H_ + (size_t)dpair * (2 * H_);
  const int ebase = lane << 8;
  const int sw = lane & 7;

  f2 acc = {0.0f, 0.0f};
  const f2 one2 = {1.0f, 1.0f};

#pragma unroll 4
  for (int g = 0; g < 64; ++g) {
    const int eoff = ebase + ((g ^ sw) << 2);
    const f2 E01 = *(const f2*)&Es[eoff];          // ds_read_b64: aligned pair
    const f2 E23 = *(const f2*)&Es[eoff + 2];
    const f2 dq0 = *(const f2*)(dpi + (g << 3));   // uniform -> SGPR pairs
    const f2 dq1 = *(const f2*)(dpi + (g << 3) + 2);
    const f2 dq2 = *(const f2*)(dpi + (g << 3) + 4);
    const f2 dq3 = *(const f2*)(dpi + (g << 3) + 6);
    const f2 w01 = *(const f2*)(v + (g << 2));     // uniform -> SGPR pair
    const f2 w23 = *(const f2*)(v + (g << 2) + 2);

    const f2 m0 = pk_fma_dq_elo(dq0, E01, one2);   // {1+E0*dA0, 1+E0*dB0}
    const f2 m1 = pk_fma_dq_ehi(dq1, E01, one2);
    const f2 m2 = pk_fma_dq_elo(dq2, E23, one2);
    const f2 m3 = pk_fma_dq_ehi(dq3, E23, one2);
    const f2 pa = pk_mul(m0, m1);
    const f2 pb = pk_mul(m2, m3);
    const f2 n01 = pk_fma_whi(w01, m0, pk_mul_wlo(w01, m1));
    const f2 n23 = pk_fma_whi(w23, m2, pk_mul_wlo(w23, m3));
    const f2 num = pk_fma(n01, pb, pk_mul(n23, pa));
    const f2 den = pk_mul(pa, pb);
    f2 r;
    r.x = __builtin_amdgcn_rcpf(den.x);
    r.y = __builtin_amdgcn_rcpf(den.y);
    acc = pk_fma(num, r, acc);
  }

  const int d = dpair << 1;
  float* orow = out + (size_t)(b * DEC_ + d) * ENC_ + e0 + lane;
  orow[0] = -2.0f * acc.x;
  orow[ENC_] = -2.0f * acc.y;
}

// ---------------- Kernel 2b: in-place row log_softmax ----------------
// 1 row (1024 f32) per block, 256 thr x float4.

__global__ __launch_bounds__(256) void lsm_k(float* __restrict__ out) {
  const int row = blockIdx.x;            // 0..1023
  float* p = out + (size_t)row * ENC_;
  const int tid = threadIdx.x;
  const int lane = tid & 63, wid = tid >> 6;

  __shared__ float rm[4], rs[4];

  float4 x = *(const float4*)(p + 4 * tid);

  float m = fmaxf(fmaxf(x.x, x.y), fmaxf(x.z, x.w));
#pragma unroll
  for (int o = 32; o >= 1; o >>= 1) m = fmaxf(m, __shfl_xor(m, o, 64));
  if (lane == 0) rm[wid] = m;
  __syncthreads();
  const float M = fmaxf(fmaxf(rm[0], rm[1]), fmaxf(rm[2], rm[3]));

  const float L2E = 1.4426950408889634f;
  const float LN2 = 0.6931471805599453f;
  float z = __builtin_amdgcn_exp2f((x.x - M) * L2E) +
            __builtin_amdgcn_exp2f((x.y - M) * L2E) +
            __builtin_amdgcn_exp2f((x.z - M) * L2E) +
            __builtin_amdgcn_exp2f((x.w - M) * L2E);
#pragma unroll
  for (int o = 32; o >= 1; o >>= 1) z += __shfl_xor(z, o, 64);
  if (lane == 0) rs[wid] = z;
  __syncthreads();
  const float S = (rs[0] + rs[1]) + (rs[2] + rs[3]);

  const float lse = M + LN2 * __builtin_amdgcn_logf(S);
  x.x -= lse; x.y -= lse; x.z -= lse; x.w -= lse;
  *(float4*)(p + 4 * tid) = x;
}

extern "C" void kernel_launch(void* const* d_in, const int* in_sizes, int n_in,
                              void* d_out, int out_size, void* d_ws, size_t ws_size,
                              hipStream_t stream) {
  const float* xd = (const float*)d_in[0];  // (4,256,256)
  const float* xe = (const float*)d_in[1];  // (4,1024,256)
  const float* w1 = (const float*)d_in[2];  // (256,256)
  const float* w2 = (const float*)d_in[3];  // (256,256)
  const float* v  = (const float*)d_in[4];  // (256,)
  float* out = (float*)d_out;               // (4,256,1024)

  float* encE = (float*)d_ws;                          // 4 MB: [B][H][ENC]
  float* decEi = encE + (size_t)B_ * H_ * ENC_;        // 1 MB: [B][dpair][H][2]

  gemm_mfma<<<320, 256, 0, stream>>>(w1, xe, xd, w2, encE, decEi);
  scores_k<<<512, 1024, 0, stream>>>(encE, decEi, v, out);
  lsm_k<<<B_ * DEC_, 256, 0, stream>>>(out);
}

// Round 16
// 39.377 us; speedup vs baseline: 1.1891x; 1.1051x over previous
//
#include <hip/hip_runtime.h>
#include <hip/hip_bf16.h>

// PointerNetwork: scores[b,d,e] = sum_h v[h]*tanh(dec_t[b,d,h] + enc_t[b,e,h]),
// out = log_softmax(scores, axis=e).  B=4, DEC=256, ENC=1024, H=256, fp32.
//
// tanh(a+b) = 1 - 2/(1 + e^{2a}e^{2b}).
//   K1 (MFMA bf16 + LDS dbuf): encE = exp2(SC*(x_enc.w1));
//       dec side writes decEi INTERLEAVED [dpair][h][2].
//   K2a scores: h-major Es [h][64e] -> conflict-free ds_read (R14 diagnosis);
//       VOP3P bundle with f2 VGPR-pair E operands ({E_h, E_h+1} from two
//       b32 reads) + op_sel lo/hi select (R15 fix: VOP3P src must be 64-bit
//       pairs; scalar-VGPR operand does not assemble). dq/w = SGPR pairs.
//   K2b lsm: in-place row log_softmax on d_out.

#define B_ 4
#define DEC_ 256
#define ENC_ 1024
#define H_ 256

using bf16x8 = __attribute__((ext_vector_type(8))) short;
using f32x4 = __attribute__((ext_vector_type(4))) float;
using f2 = __attribute__((ext_vector_type(2))) float;

__device__ inline short f2bf(float f) {
  union { float f; unsigned u; } x; x.f = f;
  return (short)((x.u + 0x8000u) >> 16);   // round-to-nearest
}

// ---- forced VOP3P packed-f32 helpers (all operands 64-bit pairs) ----
static __device__ __forceinline__ f2 pk_mul(f2 a, f2 b) {
  f2 d; asm("v_pk_mul_f32 %0, %1, %2" : "=v"(d) : "v"(a), "v"(b)); return d;
}
static __device__ __forceinline__ f2 pk_fma(f2 a, f2 b, f2 c) {
  f2 d; asm("v_pk_fma_f32 %0, %1, %2, %3" : "=v"(d) : "v"(a), "v"(b), "v"(c)); return d;
}
// m = dq * bcast(e01.lo) + c   (dq = SGPR pair; e01 = VGPR pair)
static __device__ __forceinline__ f2 pk_fma_dq_elo(f2 dq, f2 e01, f2 c) {
  f2 d; asm("v_pk_fma_f32 %0, %1, %2, %3 op_sel:[0,0,0] op_sel_hi:[1,0,1]"
            : "=v"(d) : "s"(dq), "v"(e01), "v"(c)); return d;
}
// m = dq * bcast(e01.hi) + c
static __device__ __forceinline__ f2 pk_fma_dq_ehi(f2 dq, f2 e01, f2 c) {
  f2 d; asm("v_pk_fma_f32 %0, %1, %2, %3 op_sel:[0,1,0] op_sel_hi:[1,1,1]"
            : "=v"(d) : "s"(dq), "v"(e01), "v"(c)); return d;
}
// t = bcast(w.lo) * m   (w in SGPR pair)
static __device__ __forceinline__ f2 pk_mul_wlo(f2 w, f2 m) {
  f2 d; asm("v_pk_mul_f32 %0, %1, %2 op_sel:[0,0] op_sel_hi:[0,1]"
            : "=v"(d) : "s"(w), "v"(m)); return d;
}
// n = bcast(w.hi) * m + t
static __device__ __forceinline__ f2 pk_fma_whi(f2 w, f2 m, f2 c) {
  f2 d; asm("v_pk_fma_f32 %0, %1, %2, %3 op_sel:[1,0,0] op_sel_hi:[1,1,1]"
            : "=v"(d) : "s"(w), "v"(m), "v"(c)); return d;
}

// ---------------- Kernel 1: dual GEMM (A . B^T) via MFMA + LDS dbuf ----------------
#define LDK 72   // padded row stride in shorts

__global__ __launch_bounds__(256) void gemm_mfma(
    const float* __restrict__ w1, const float* __restrict__ xe,
    const float* __restrict__ xd, const float* __restrict__ w2,
    float* __restrict__ encE, float* __restrict__ decEi) {
  const int blk = blockIdx.x;
  const float* A;
  const float* Bsrc;
  float* C;
  int ldc, m0, n0, decside;
  if (blk < 256) {
    const int b = blk >> 6;
    const int t = blk & 63;            // 4 (h) x 16 (e)
    m0 = (t >> 4) << 6; n0 = (t & 15) << 6;
    A = w1;
    Bsrc = xe + (size_t)b * ENC_ * H_;
    C = encE + (size_t)b * H_ * ENC_;
    ldc = ENC_;
    decside = 0;
  } else {
    const int blk2 = blk - 256;
    const int b = blk2 >> 4;
    const int t = blk2 & 15;           // 4 (d) x 4 (h)
    m0 = (t >> 2) << 6; n0 = (t & 3) << 6;
    A = xd + (size_t)b * DEC_ * H_;
    Bsrc = w2;
    C = decEi + (size_t)b * DEC_ * H_;
    ldc = H_;
    decside = 1;
  }
  const int K = H_;
  const int tid = threadIdx.x;
  const int wave = tid >> 6, lane = tid & 63;
  const int wm = (wave >> 1) << 5, wn = (wave & 1) << 5;
  const int fr = lane & 15;
  const int fk = (lane >> 4) << 3;

  __shared__ short As[2][64][LDK];
  __shared__ short Bs[2][64][LDK];

  const int srow = tid >> 2;
  const int skq = (tid & 3) << 4;
  const float* ag = A + (size_t)(m0 + srow) * K + skq;
  const float* bg = Bsrc + (size_t)(n0 + srow) * K + skq;

  float4 ra[4], rb[4];
#define LDCHUNK(K0)                                                    \
  {                                                                    \
    _Pragma("unroll")                                                  \
    for (int i = 0; i < 4; ++i) {                                      \
      ra[i] = *(const float4*)(ag + (K0) + 4 * i);                     \
      rb[i] = *(const float4*)(bg + (K0) + 4 * i);                     \
    }                                                                  \
  }
#define STCHUNK(BUF)                                                   \
  {                                                                    \
    _Pragma("unroll")                                                  \
    for (int j = 0; j < 2; ++j) {                                      \
      bf16x8 pa, pb;                                                   \
      pa[0] = f2bf(ra[2 * j].x);     pa[1] = f2bf(ra[2 * j].y);        \
      pa[2] = f2bf(ra[2 * j].z);     pa[3] = f2bf(ra[2 * j].w);        \
      pa[4] = f2bf(ra[2 * j + 1].x); pa[5] = f2bf(ra[2 * j + 1].y);    \
      pa[6] = f2bf(ra[2 * j + 1].z); pa[7] = f2bf(ra[2 * j + 1].w);    \
      pb[0] = f2bf(rb[2 * j].x);     pb[1] = f2bf(rb[2 * j].y);        \
      pb[2] = f2bf(rb[2 * j].z);     pb[3] = f2bf(rb[2 * j].w);        \
      pb[4] = f2bf(rb[2 * j + 1].x); pb[5] = f2bf(rb[2 * j + 1].y);    \
      pb[6] = f2bf(rb[2 * j + 1].z); pb[7] = f2bf(rb[2 * j + 1].w);    \
      *(bf16x8*)&As[BUF][srow][skq + 8 * j] = pa;                      \
      *(bf16x8*)&Bs[BUF][srow][skq + 8 * j] = pb;                      \
    }                                                                  \
  }

  f32x4 acc[2][2] = {};

#define COMPUTE(BUF)                                                   \
  {                                                                    \
    _Pragma("unroll")                                                  \
    for (int kk = 0; kk < 2; ++kk) {                                   \
      bf16x8 af[2], bff[2];                                            \
      _Pragma("unroll")                                                \
      for (int mi = 0; mi < 2; ++mi)                                   \
        af[mi] = *(const bf16x8*)&As[BUF][wm + (mi << 4) + fr][(kk << 5) + fk]; \
      _Pragma("unroll")                                                \
      for (int ni = 0; ni < 2; ++ni)                                   \
        bff[ni] = *(const bf16x8*)&Bs[BUF][wn + (ni << 4) + fr][(kk << 5) + fk]; \
      _Pragma("unroll")                                                \
      for (int mi = 0; mi < 2; ++mi)                                   \
        _Pragma("unroll")                                              \
        for (int ni = 0; ni < 2; ++ni)                                 \
          acc[mi][ni] = __builtin_amdgcn_mfma_f32_16x16x32_bf16(       \
              af[mi], bff[ni], acc[mi][ni], 0, 0, 0);                  \
    }                                                                  \
  }

  LDCHUNK(0)
  STCHUNK(0)
  __syncthreads();
  LDCHUNK(64) COMPUTE(0) STCHUNK(1) __syncthreads();
  LDCHUNK(128) COMPUTE(1) STCHUNK(0) __syncthreads();
  LDCHUNK(192) COMPUTE(0) STCHUNK(1) __syncthreads();
  COMPUTE(1)

  const float SC = 2.8853900817779268f;  // 2*log2(e)
#pragma unroll
  for (int mi = 0; mi < 2; ++mi) {
#pragma unroll
    for (int ni = 0; ni < 2; ++ni) {
      const int row = m0 + wm + (mi << 4) + ((lane >> 4) << 2);
      const int col = n0 + wn + (ni << 4) + (lane & 15);
#pragma unroll
      for (int r = 0; r < 4; ++r) {
        const float val = __builtin_amdgcn_exp2f(acc[mi][ni][r] * SC);
        if (decside) {
          // interleaved: [(d>>1)][h][d&1]
          const int rr = row + r;
          C[((size_t)(rr >> 1) * H_ + col) * 2 + (rr & 1)] = val;
        } else {
          C[(size_t)(row + r) * ldc + col] = val;
        }
      }
    }
  }
}

// ---------------- Kernel 2a: raw scores (h-major LDS, forced VOP3P) ----------------
// Block = 1024 thr = 16 waves, covers 64 e x 32 d. Es = [h(256)][e(64)] fp32
// (64KB): lane l reads &Es[h*64 + l] -> 64 consecutive lanes, conflict-free
// ds_read_b32 with imm offsets. Staging = direct copy (no transpose).
// E operand = f2 {E_h, E_h+1} from two b32 reads (op_sel lo/hi). dq/w = SGPR
// pairs via uniform s_loads. Writes raw -2*acc. Grid 512 -> 2 blk/CU.

__global__ __launch_bounds__(1024) void scores_k(
    const float* __restrict__ encE, const float* __restrict__ decEi,
    const float* __restrict__ v, float* __restrict__ out) {
  const int bid = blockIdx.x;            // 0..511
  // XCD pinning: batch b -> XCDs {2b, 2b+1}
  const int xcd = bid & 7;
  const int b = xcd >> 1;
  const int rem = ((bid >> 3) << 1) | (xcd & 1);   // 0..127 within batch
  const int es = rem & 15;               // e-slice (64 e)
  const int d0 = (rem >> 4) << 5;        // d-group of 32
  const int tid = threadIdx.x;
  const int lane = tid & 63;
  const int wid = __builtin_amdgcn_readfirstlane(tid >> 6);  // 0..15

  __shared__ __align__(16) float Es[H_ * 64];    // [h][e] h-major, 64KB

  const int e0 = es << 6;
  const float* egbase = encE + (size_t)b * H_ * ENC_ + e0;

  // ---- stage (direct copy): 4 x {float4 load + ds_write_b128} / thread ----
#pragma unroll
  for (int s = 0; s < 4; ++s) {
    const int fi = (s << 10) + tid;      // 0..4095
    const int h = fi >> 4;               // 0..255
    const int c = fi & 15;               // float4 chunk along e
    const float4 x = *(const float4*)(egbase + (size_t)h * ENC_ + (c << 2));
    *(float4*)&Es[(h << 6) + (c << 2)] = x;
  }
  __syncthreads();

  const int dpair = (d0 >> 1) + wid;     // d = 2*dpair, 2*dpair+1
  const float* dpi = decEi + (size_t)b * DEC_ * H_ + (size_t)dpair * (2 * H_);
  const float* epl = Es + lane;

  f2 acc = {0.0f, 0.0f};
  const f2 one2 = {1.0f, 1.0f};

#pragma unroll 4
  for (int g = 0; g < 64; ++g) {
    // conflict-free b32 reads; pack adjacent h into register pairs
    f2 E01, E23;
    E01.x = epl[(4 * g + 0) << 6];
    E01.y = epl[(4 * g + 1) << 6];
    E23.x = epl[(4 * g + 2) << 6];
    E23.y = epl[(4 * g + 3) << 6];
    const f2 dq0 = *(const f2*)(dpi + (g << 3));   // uniform -> SGPR pairs
    const f2 dq1 = *(const f2*)(dpi + (g << 3) + 2);
    const f2 dq2 = *(const f2*)(dpi + (g << 3) + 4);
    const f2 dq3 = *(const f2*)(dpi + (g << 3) + 6);
    const f2 w01 = *(const f2*)(v + (g << 2));     // uniform -> SGPR pair
    const f2 w23 = *(const f2*)(v + (g << 2) + 2);

    const f2 m0 = pk_fma_dq_elo(dq0, E01, one2);   // {1+E0*dA0, 1+E0*dB0}
    const f2 m1 = pk_fma_dq_ehi(dq1, E01, one2);
    const f2 m2 = pk_fma_dq_elo(dq2, E23, one2);
    const f2 m3 = pk_fma_dq_ehi(dq3, E23, one2);
    const f2 pa = pk_mul(m0, m1);
    const f2 pb = pk_mul(m2, m3);
    const f2 n01 = pk_fma_whi(w01, m0, pk_mul_wlo(w01, m1));
    const f2 n23 = pk_fma_whi(w23, m2, pk_mul_wlo(w23, m3));
    const f2 num = pk_fma(n01, pb, pk_mul(n23, pa));
    const f2 den = pk_mul(pa, pb);
    f2 r;
    r.x = __builtin_amdgcn_rcpf(den.x);
    r.y = __builtin_amdgcn_rcpf(den.y);
    acc = pk_fma(num, r, acc);
  }

  const int d = dpair << 1;
  float* orow = out + (size_t)(b * DEC_ + d) * ENC_ + e0 + lane;
  orow[0] = -2.0f * acc.x;
  orow[ENC_] = -2.0f * acc.y;
}

// ---------------- Kernel 2b: in-place row log_softmax ----------------
// 1 row (1024 f32) per block, 256 thr x float4.

__global__ __launch_bounds__(256) void lsm_k(float* __restrict__ out) {
  const int row = blockIdx.x;            // 0..1023
  float* p = out + (size_t)row * ENC_;
  const int tid = threadIdx.x;
  const int lane = tid & 63, wid = tid >> 6;

  __shared__ float rm[4], rs[4];

  float4 x = *(const float4*)(p + 4 * tid);

  float m = fmaxf(fmaxf(x.x, x.y), fmaxf(x.z, x.w));
#pragma unroll
  for (int o = 32; o >= 1; o >>= 1) m = fmaxf(m, __shfl_xor(m, o, 64));
  if (lane == 0) rm[wid] = m;
  __syncthreads();
  const float M = fmaxf(fmaxf(rm[0], rm[1]), fmaxf(rm[2], rm[3]));

  const float L2E = 1.4426950408889634f;
  const float LN2 = 0.6931471805599453f;
  float z = __builtin_amdgcn_exp2f((x.x - M) * L2E) +
            __builtin_amdgcn_exp2f((x.y - M) * L2E) +
            __builtin_amdgcn_exp2f((x.z - M) * L2E) +
            __builtin_amdgcn_exp2f((x.w - M) * L2E);
#pragma unroll
  for (int o = 32; o >= 1; o >>= 1) z += __shfl_xor(z, o, 64);
  if (lane == 0) rs[wid] = z;
  __syncthreads();
  const float S = (rs[0] + rs[1]) + (rs[2] + rs[3]);

  const float lse = M + LN2 * __builtin_amdgcn_logf(S);
  x.x -= lse; x.y -= lse; x.z -= lse; x.w -= lse;
  *(float4*)(p + 4 * tid) = x;
}

extern "C" void kernel_launch(void* const* d_in, const int* in_sizes, int n_in,
                              void* d_out, int out_size, void* d_ws, size_t ws_size,
                              hipStream_t stream) {
  const float* xd = (const float*)d_in[0];  // (4,256,256)
  const float* xe = (const float*)d_in[1];  // (4,1024,256)
  const float* w1 = (const float*)d_in[2];  // (256,256)
  const float* w2 = (const float*)d_in[3];  // (256,256)
  const float* v  = (const float*)d_in[4];  // (256,)
  float* out = (float*)d_out;               // (4,256,1024)

  float* encE = (float*)d_ws;                          // 4 MB: [B][H][ENC]
  float* decEi = encE + (size_t)B_ * H_ * ENC_;        // 1 MB: [B][dpair][H][2]

  gemm_mfma<<<320, 256, 0, stream>>>(w1, xe, xd, w2, encE, decEi);
  scores_k<<<512, 1024, 0, stream>>>(encE, decEi, v, out);
  lsm_k<<<B_ * DEC_, 256, 0, stream>>>(out);
}